// Round 1
// baseline (142.668 us; speedup 1.0000x reference)
//
#include <hip/hip_runtime.h>
#include <hip/hip_bf16.h>
#include <cstdint>

#define N_NODES 8192
#define F_IN    512
#define D_O     64
#define H_N     8
#define NOUT    512   // H_N * D_O
#define MAXD    512   // max supported degree (mean 33, std 5.7 -> 512 is unreachable)

typedef __attribute__((ext_vector_type(8))) short short8;
typedef __attribute__((ext_vector_type(4))) float f32x4;

static __device__ __forceinline__ ushort f2bf(float f) {
  union { float f; uint32_t u; } v; v.f = f;
  uint32_t r = v.u + 0x7FFFu + ((v.u >> 16) & 1u);  // round-to-nearest-even
  return (ushort)(r >> 16);
}

// ---------------------------------------------------------------------------
// Kernel 1: Wh = x @ W   (x: [8192,512] f32, W: [8,512,64] f32 -> Wh [8192,512] f32)
// 128x128 tile, BK=32, 4 waves (2x2), each wave 64x64 via 4x4 mfma_f32_16x16x32_bf16.
// ---------------------------------------------------------------------------
__global__ __launch_bounds__(256) void gemm_xw(const float* __restrict__ x,
                                               const float* __restrict__ W,
                                               float* __restrict__ Wh) {
  __shared__ ushort As[128][40];   // [row][k], +8 pad -> 80B stride (2-way max, free)
  __shared__ ushort Bs[128][40];   // [col][k] (transposed so frag read is ds_read_b128)

  const int tid  = threadIdx.x;
  const int lane = tid & 63;
  const int wv   = tid >> 6;       // 0..3
  const int wr   = wv >> 1, wc = wv & 1;
  const int r0   = blockIdx.y * 128;
  const int c0   = blockIdx.x * 128;
  const int lm   = lane & 15;
  const int lk   = (lane >> 4) * 8;

  f32x4 acc[4][4];
  #pragma unroll
  for (int m2 = 0; m2 < 4; ++m2)
    #pragma unroll
    for (int n2 = 0; n2 < 4; ++n2)
      acc[m2][n2] = (f32x4){0.f, 0.f, 0.f, 0.f};

  // A staging: 8 threads/row cover k=32 (float4 each), 32 rows/pass, 4 passes
  const int tr = tid >> 3;
  const int tk = (tid & 7) * 4;
  // B staging: thread -> (c_local, k_half); reads W column-wise (coalesced over d)
  const int cl    = tid & 127;
  const int khalf = tid >> 7;
  const int ch    = c0 + cl;
  const int bh    = ch >> 6;       // head
  const int bd    = ch & 63;       // d within head

  for (int k0 = 0; k0 < F_IN; k0 += 32) {
    __syncthreads();
    #pragma unroll
    for (int pp = 0; pp < 4; ++pp) {
      int r = pp * 32 + tr;
      const float4 vv = *(const float4*)&x[(size_t)(r0 + r) * F_IN + k0 + tk];
      ushort4 u;
      u.x = f2bf(vv.x); u.y = f2bf(vv.y); u.z = f2bf(vv.z); u.w = f2bf(vv.w);
      *(ushort4*)&As[r][tk] = u;
    }
    {
      union { ushort u[16]; uint4 q[2]; } t;
      const float* wp = &W[((size_t)bh * F_IN + k0 + khalf * 16) * D_O + bd];
      #pragma unroll
      for (int kk = 0; kk < 16; ++kk) t.u[kk] = f2bf(wp[(size_t)kk * D_O]);
      *(uint4*)&Bs[cl][khalf * 16]     = t.q[0];
      *(uint4*)&Bs[cl][khalf * 16 + 8] = t.q[1];
    }
    __syncthreads();

    short8 af[4], bf[4];
    #pragma unroll
    for (int m2 = 0; m2 < 4; ++m2)
      af[m2] = *(const short8*)&As[wr * 64 + m2 * 16 + lm][lk];
    #pragma unroll
    for (int n2 = 0; n2 < 4; ++n2)
      bf[n2] = *(const short8*)&Bs[wc * 64 + n2 * 16 + lm][lk];
    #pragma unroll
    for (int m2 = 0; m2 < 4; ++m2)
      #pragma unroll
      for (int n2 = 0; n2 < 4; ++n2)
        acc[m2][n2] = __builtin_amdgcn_mfma_f32_16x16x32_bf16(af[m2], bf[n2], acc[m2][n2], 0, 0, 0);
  }

  // epilogue: D row = (lane>>4)*4 + r, col = lane&15  [measured layout, guide §3]
  const int rowb = (lane >> 4) * 4;
  #pragma unroll
  for (int m2 = 0; m2 < 4; ++m2) {
    #pragma unroll
    for (int n2 = 0; n2 < 4; ++n2) {
      const int c     = c0 + wc * 64 + n2 * 16 + lm;
      const int rbase = r0 + wr * 64 + m2 * 16 + rowb;
      #pragma unroll
      for (int r = 0; r < 4; ++r)
        Wh[(size_t)(rbase + r) * NOUT + c] = acc[m2][n2][r];
    }
  }
}

// ---------------------------------------------------------------------------
// Kernel 2: f1[i][h] = sum_d Wh[i][h*64+d]*a1[h][d];  f2 likewise.
// One wave per (i,h); lane = d. Coalesced, shuffle-reduced.
// ---------------------------------------------------------------------------
__global__ __launch_bounds__(256) void f_proj(const float* __restrict__ Wh,
                                              const float* __restrict__ a1,
                                              const float* __restrict__ a2,
                                              float* __restrict__ f1,
                                              float* __restrict__ f2) {
  const int gw   = blockIdx.x * 4 + (threadIdx.x >> 6);  // (i*8 + h)
  const int lane = threadIdx.x & 63;
  const int i = gw >> 3, h = gw & 7;
  const float wv = Wh[(size_t)i * NOUT + h * D_O + lane];
  float v1 = wv * a1[h * D_O + lane];
  float v2 = wv * a2[h * D_O + lane];
  #pragma unroll
  for (int o = 32; o; o >>= 1) {
    v1 += __shfl_xor(v1, o);
    v2 += __shfl_xor(v2, o);
  }
  if (lane == 0) { f1[gw] = v1; f2[gw] = v2; }
}

// ---------------------------------------------------------------------------
// Kernel 3: one block (512 thr) per row i.
//   A) scan adj row, deterministic compaction of neighbor indices (prefix scan)
//   B) logits[n][h] = leaky_relu(f1[i][h] + f2[j][h])  into LDS (pad 9 vs bank)
//   C) wave w = head w: max + exp-sum reduce, store exp in place, invs[w]
//   D) thread c: out[i][c] = (sum_n p[n][h]*Wh[j_n][c]) * invs[h]
// ---------------------------------------------------------------------------
__global__ __launch_bounds__(512) void gat_attn(const float* __restrict__ adj,
                                                const float* __restrict__ Wh,
                                                const float* __restrict__ f1,
                                                const float* __restrict__ f2,
                                                float* __restrict__ out) {
  const int i    = blockIdx.x;
  const int tid  = threadIdx.x;
  const int lane = tid & 63;
  const int w    = tid >> 6;     // wave id 0..7 == head in phases C/D

  __shared__ int   nbr[MAXD];
  __shared__ float p[MAXD][9];   // [n][h], pad to 9 -> conflict-free column walk
  __shared__ float f1s[8], invs[8];
  __shared__ int   wsum[8];

  if (tid < 8) f1s[tid] = f1[(size_t)i * H_N + tid];

  // --- A: scan + deterministic compaction --------------------------------
  const float* arow = adj + (size_t)i * N_NODES;
  uint32_t bits = 0;
  #pragma unroll
  for (int u = 0; u < 4; ++u) {
    const float4 a = *(const float4*)&arow[u * 2048 + tid * 4];
    if (a.x > 0.f) bits |= 1u << (u * 4 + 0);
    if (a.y > 0.f) bits |= 1u << (u * 4 + 1);
    if (a.z > 0.f) bits |= 1u << (u * 4 + 2);
    if (a.w > 0.f) bits |= 1u << (u * 4 + 3);
  }
  const int cnt = __popc(bits);
  int v = cnt;                                  // inclusive scan within wave
  #pragma unroll
  for (int o = 1; o < 64; o <<= 1) {
    int u = __shfl_up(v, o);
    if (lane >= o) v += u;
  }
  if (lane == 63) wsum[w] = v;
  __syncthreads();
  int base = 0, total = 0;
  #pragma unroll
  for (int ww = 0; ww < 8; ++ww) {
    int s = wsum[ww];
    if (ww < w) base += s;
    total += s;
  }
  const int deg = min(total, MAXD);
  int off = base + v - cnt;                     // exclusive position
  #pragma unroll
  for (int u = 0; u < 4; ++u)
    #pragma unroll
    for (int b = 0; b < 4; ++b)
      if (bits & (1u << (u * 4 + b))) {
        if (off < MAXD) nbr[off] = u * 2048 + tid * 4 + b;
        ++off;
      }
  __syncthreads();

  // --- B: logits ---------------------------------------------------------
  for (int idx = tid; idx < deg * H_N; idx += 512) {
    const int n = idx >> 3, h = idx & 7;
    const int j = nbr[n];
    float l = f1s[h] + f2[(size_t)j * H_N + h];
    l = l > 0.f ? l : 0.2f * l;                 // leaky_relu alpha=0.2
    p[n][h] = l;
  }
  __syncthreads();

  // --- C: per-head softmax (wave w owns head w) --------------------------
  {
    float m = -3.0e38f;
    for (int n = lane; n < deg; n += 64) m = fmaxf(m, p[n][w]);
    #pragma unroll
    for (int o = 32; o; o >>= 1) m = fmaxf(m, __shfl_xor(m, o));
    float s = 0.f;
    for (int n = lane; n < deg; n += 64) {
      const float e = __expf(p[n][w] - m);
      p[n][w] = e;
      s += e;
    }
    #pragma unroll
    for (int o = 32; o; o >>= 1) s += __shfl_xor(s, o);
    if (lane == 0) invs[w] = 1.0f / s;
  }
  __syncthreads();

  // --- D: weighted accumulation -----------------------------------------
  float acc = 0.f;
  #pragma unroll 4
  for (int n = 0; n < deg; ++n)
    acc += p[n][w] * Wh[(size_t)nbr[n] * NOUT + tid];
  out[(size_t)i * NOUT + tid] = acc * invs[w];
}

extern "C" void kernel_launch(void* const* d_in, const int* in_sizes, int n_in,
                              void* d_out, int out_size, void* d_ws, size_t ws_size,
                              hipStream_t stream) {
  const float* x   = (const float*)d_in[0];
  const float* adj = (const float*)d_in[1];
  const float* W   = (const float*)d_in[2];
  const float* a1  = (const float*)d_in[3];
  const float* a2  = (const float*)d_in[4];
  float* out = (float*)d_out;

  float* Wh = (float*)d_ws;                       // 8192*512 f32 = 16 MB
  float* f1 = Wh + (size_t)N_NODES * NOUT;        // 64K f32
  float* f2 = f1 + (size_t)N_NODES * H_N;         // 64K f32

  hipLaunchKernelGGL(gemm_xw, dim3(NOUT / 128, N_NODES / 128), dim3(256), 0, stream,
                     x, W, Wh);
  hipLaunchKernelGGL(f_proj, dim3(N_NODES * H_N / 4), dim3(256), 0, stream,
                     Wh, a1, a2, f1, f2);
  hipLaunchKernelGGL(gat_attn, dim3(N_NODES), dim3(512), 0, stream,
                     adj, Wh, f1, f2, out);
}

// Round 5
// 111.018 us; speedup vs baseline: 1.2851x; 1.2851x over previous
//
#include <hip/hip_runtime.h>
#include <hip/hip_bf16.h>
#include <cstdint>

#define N_NODES 8192
#define F_IN    512
#define D_O     64
#define H_N     8
#define NOUT    512   // H_N * D_O
#define MAXD    512   // max supported degree (mean ~33; 512 unreachable)

typedef __attribute__((ext_vector_type(8))) short short8;
typedef __attribute__((ext_vector_type(4))) float f32x4;

static __device__ __forceinline__ ushort f2bf(float f) {
  union { float f; uint32_t u; } v; v.f = f;
  uint32_t r = v.u + 0x7FFFu + ((v.u >> 16) & 1u);  // RNE
  return (ushort)(r >> 16);
}
static __device__ __forceinline__ float bf2f(ushort u) {
  union { uint32_t u; float f; } v; v.u = ((uint32_t)u) << 16;
  return v.f;
}

// ---------------------------------------------------------------------------
// Kernel 0: xb = bf16(x);  Wt[h][d][k] = bf16(W[h][k][d])
// ---------------------------------------------------------------------------
__global__ __launch_bounds__(256) void convert(const float* __restrict__ x,
                                               const float* __restrict__ W,
                                               ushort* __restrict__ xb,
                                               ushort* __restrict__ Wt) {
  const int gid    = blockIdx.x * 256 + threadIdx.x;
  const int stride = gridDim.x * 256;
  const int NQ = N_NODES * F_IN / 4;          // 1,048,576 float4s
  for (int q = gid; q < NQ; q += stride) {
    const float4 v = ((const float4*)x)[q];
    ushort4 u;
    u.x = f2bf(v.x); u.y = f2bf(v.y); u.z = f2bf(v.z); u.w = f2bf(v.w);
    ((ushort4*)xb)[q] = u;
  }
  const int NW = H_N * D_O * F_IN;            // 262,144
  for (int t = gid; t < NW; t += stride) {
    const int h = t >> 15, rem = t & 32767;
    const int d = rem >> 9, k = rem & 511;
    Wt[t] = f2bf(W[(size_t)h * F_IN * D_O + (size_t)k * D_O + d]);
  }
}

// ---------------------------------------------------------------------------
// Kernel 1: Whb = bf16( xb @ Wt^T )   (both operands [row][k] bf16, BK=32)
// 128x128 tile, 4 waves (2x2), 4x4 mfma_f32_16x16x32_bf16 per wave.
// ---------------------------------------------------------------------------
__global__ __launch_bounds__(256) void gemm_xw(const ushort* __restrict__ xb,
                                               const ushort* __restrict__ Wt,
                                               ushort* __restrict__ Whb) {
  __shared__ ushort As[128][40];   // pad -> 80B stride, 2-way bank alias (free)
  __shared__ ushort Bs[128][40];

  const int tid  = threadIdx.x;
  const int lane = tid & 63;
  const int wv   = tid >> 6;
  const int wr   = wv >> 1, wc = wv & 1;
  const int r0   = blockIdx.y * 128;
  const int c0   = blockIdx.x * 128;
  const int lm   = lane & 15;
  const int lk   = (lane >> 4) * 8;

  f32x4 acc[4][4];
  #pragma unroll
  for (int m2 = 0; m2 < 4; ++m2)
    #pragma unroll
    for (int n2 = 0; n2 < 4; ++n2)
      acc[m2][n2] = (f32x4){0.f, 0.f, 0.f, 0.f};

  for (int k0 = 0; k0 < F_IN; k0 += 32) {
    __syncthreads();
    #pragma unroll
    for (int half = 0; half < 2; ++half) {
      const int cid = half * 256 + tid;       // 0..511
      const int row = cid >> 2, ck = (cid & 3) * 8;
      *(short8*)&As[row][ck] = *(const short8*)&xb[(size_t)(r0 + row) * F_IN + k0 + ck];
      *(short8*)&Bs[row][ck] = *(const short8*)&Wt[(size_t)(c0 + row) * F_IN + k0 + ck];
    }
    __syncthreads();

    short8 af[4], bf[4];
    #pragma unroll
    for (int m2 = 0; m2 < 4; ++m2)
      af[m2] = *(const short8*)&As[wr * 64 + m2 * 16 + lm][lk];
    #pragma unroll
    for (int n2 = 0; n2 < 4; ++n2)
      bf[n2] = *(const short8*)&Bs[wc * 64 + n2 * 16 + lm][lk];
    #pragma unroll
    for (int m2 = 0; m2 < 4; ++m2)
      #pragma unroll
      for (int n2 = 0; n2 < 4; ++n2)
        acc[m2][n2] = __builtin_amdgcn_mfma_f32_16x16x32_bf16(af[m2], bf[n2], acc[m2][n2], 0, 0, 0);
  }

  const int rowb = (lane >> 4) * 4;           // D: row=(lane>>4)*4+r, col=lane&15
  #pragma unroll
  for (int m2 = 0; m2 < 4; ++m2) {
    #pragma unroll
    for (int n2 = 0; n2 < 4; ++n2) {
      const int c     = c0 + wc * 64 + n2 * 16 + lm;
      const int rbase = r0 + wr * 64 + m2 * 16 + rowb;
      #pragma unroll
      for (int r = 0; r < 4; ++r)
        Whb[(size_t)(rbase + r) * NOUT + c] = f2bf(acc[m2][n2][r]);
    }
  }
}

// ---------------------------------------------------------------------------
// Kernel 2: f1[i][h] = sum_d Whb[i][h*64+d]*a1[h][d]; f2 likewise.
// ---------------------------------------------------------------------------
__global__ __launch_bounds__(256) void f_proj(const ushort* __restrict__ Whb,
                                              const float* __restrict__ a1,
                                              const float* __restrict__ a2,
                                              float* __restrict__ f1,
                                              float* __restrict__ f2) {
  const int gw   = blockIdx.x * 4 + (threadIdx.x >> 6);  // i*8 + h
  const int lane = threadIdx.x & 63;
  const int i = gw >> 3, h = gw & 7;
  const float wv = bf2f(Whb[(size_t)i * NOUT + h * D_O + lane]);
  float v1 = wv * a1[h * D_O + lane];
  float v2 = wv * a2[h * D_O + lane];
  #pragma unroll
  for (int o = 32; o; o >>= 1) {
    v1 += __shfl_xor(v1, o);
    v2 += __shfl_xor(v2, o);
  }
  if (lane == 0) { f1[gw] = v1; f2[gw] = v2; }
}

// ---------------------------------------------------------------------------
// Kernel 3: one 256-thread block per row i.
// A) adj-row scan + deterministic compaction  B) logits  C) per-head softmax
// D) thread t accumulates cols {2t, 2t+1} over neighbors (ushort2 bf16 gather)
// ---------------------------------------------------------------------------
__global__ __launch_bounds__(256) void gat_attn(const uint32_t* __restrict__ adj,
                                                const ushort* __restrict__ Whb,
                                                const float* __restrict__ f1,
                                                const float* __restrict__ f2,
                                                float* __restrict__ out) {
  const int i    = blockIdx.x;
  const int tid  = threadIdx.x;
  const int lane = tid & 63;
  const int w    = tid >> 6;     // 0..3

  __shared__ int   nbr[MAXD];
  __shared__ float p[MAXD][9];
  __shared__ float f1s[8], invs[8];
  __shared__ int   wsum[4];

  if (tid < 8) f1s[tid] = f1[(size_t)i * H_N + tid];

  // --- A: scan + compaction ---------------------------------------------
  const uint32_t* arow = adj + (size_t)i * N_NODES;
  uint32_t bits = 0;
  #pragma unroll
  for (int u = 0; u < 8; ++u) {
    const uint4 a = *(const uint4*)&arow[(u * 256 + tid) * 4];
    if (a.x) bits |= 1u << (u * 4 + 0);
    if (a.y) bits |= 1u << (u * 4 + 1);
    if (a.z) bits |= 1u << (u * 4 + 2);
    if (a.w) bits |= 1u << (u * 4 + 3);
  }
  const int cnt = __popc(bits);
  int v = cnt;
  #pragma unroll
  for (int o = 1; o < 64; o <<= 1) {
    int u = __shfl_up(v, o);
    if (lane >= o) v += u;
  }
  if (lane == 63) wsum[w] = v;
  __syncthreads();
  int base = 0, total = 0;
  #pragma unroll
  for (int ww = 0; ww < 4; ++ww) {
    int s = wsum[ww];
    if (ww < w) base += s;
    total += s;
  }
  const int deg = min(total, MAXD);
  int off = base + v - cnt;
  #pragma unroll
  for (int u = 0; u < 8; ++u)
    #pragma unroll
    for (int b = 0; b < 4; ++b)
      if (bits & (1u << (u * 4 + b))) {
        if (off < MAXD) nbr[off] = (u * 256 + tid) * 4 + b;
        ++off;
      }
  __syncthreads();

  // --- B: logits ---------------------------------------------------------
  for (int idx = tid; idx < deg * H_N; idx += 256) {
    const int n = idx >> 3, h = idx & 7;
    const int j = nbr[n];
    float l = f1s[h] + f2[(size_t)j * H_N + h];
    l = l > 0.f ? l : 0.2f * l;
    p[n][h] = l;
  }
  __syncthreads();

  // --- C: softmax (wave w handles heads w and w+4) -----------------------
  #pragma unroll
  for (int hh = 0; hh < 2; ++hh) {
    const int h = w + hh * 4;
    float m = -3.0e38f;
    for (int n = lane; n < deg; n += 64) m = fmaxf(m, p[n][h]);
    #pragma unroll
    for (int o = 32; o; o >>= 1) m = fmaxf(m, __shfl_xor(m, o));
    float s = 0.f;
    for (int n = lane; n < deg; n += 64) {
      const float e = __expf(p[n][h] - m);
      p[n][h] = e;
      s += e;
    }
    #pragma unroll
    for (int o = 32; o; o >>= 1) s += __shfl_xor(s, o);
    if (lane == 0) invs[h] = 1.0f / s;
  }
  __syncthreads();

  // --- D: weighted accumulation (2 cols per thread, bf16 gather) ---------
  const int h = tid >> 5;                     // (2*tid)/64
  float acc0 = 0.f, acc1 = 0.f;
  #pragma unroll 4
  for (int n = 0; n < deg; ++n) {
    const float pv = p[n][h];
    const ushort2 u = *(const ushort2*)&Whb[(size_t)nbr[n] * NOUT + tid * 2];
    acc0 += pv * bf2f(u.x);
    acc1 += pv * bf2f(u.y);
  }
  const float inv = invs[h];
  float2 o2; o2.x = acc0 * inv; o2.y = acc1 * inv;
  *(float2*)&out[(size_t)i * NOUT + tid * 2] = o2;
}

extern "C" void kernel_launch(void* const* d_in, const int* in_sizes, int n_in,
                              void* d_out, int out_size, void* d_ws, size_t ws_size,
                              hipStream_t stream) {
  const float* x   = (const float*)d_in[0];
  const float* adj = (const float*)d_in[1];
  const float* W   = (const float*)d_in[2];
  const float* a1  = (const float*)d_in[3];
  const float* a2  = (const float*)d_in[4];
  float* out = (float*)d_out;

  ushort* Whb = (ushort*)d_ws;                          // 4M bf16 = 8 MB
  ushort* xb  = Whb + (size_t)N_NODES * NOUT;           // 4M bf16 = 8 MB
  ushort* Wt  = xb + (size_t)N_NODES * F_IN;            // 256K bf16 = 0.5 MB
  float*  f1  = (float*)(Wt + (size_t)H_N * D_O * F_IN);
  float*  f2  = f1 + (size_t)N_NODES * H_N;

  hipLaunchKernelGGL(convert, dim3(2048), dim3(256), 0, stream, x, W, xb, Wt);
  hipLaunchKernelGGL(gemm_xw, dim3(NOUT / 128, N_NODES / 128), dim3(256), 0, stream,
                     xb, Wt, Whb);
  hipLaunchKernelGGL(f_proj, dim3(N_NODES * H_N / 4), dim3(256), 0, stream,
                     Whb, a1, a2, f1, f2);
  hipLaunchKernelGGL(gat_attn, dim3(N_NODES), dim3(256), 0, stream,
                     (const uint32_t*)adj, Whb, f1, f2, out);
}

// Round 6
// 98.277 us; speedup vs baseline: 1.4517x; 1.1296x over previous
//
#include <hip/hip_runtime.h>
#include <hip/hip_bf16.h>
#include <cstdint>

#define N_NODES 8192
#define F_IN    512
#define D_O     64
#define H_N     8
#define NOUT    512   // H_N * D_O
#define MAXD    512   // max supported degree (mean ~33; 512 unreachable)

#define BM 64
#define BN 128
#define BK 64

typedef __attribute__((ext_vector_type(8))) short short8;
typedef __attribute__((ext_vector_type(4))) float f32x4;

static __device__ __forceinline__ ushort f2bf(float f) {
  union { float f; uint32_t u; } v; v.f = f;
  uint32_t r = v.u + 0x7FFFu + ((v.u >> 16) & 1u);  // RNE
  return (ushort)(r >> 16);
}
static __device__ __forceinline__ float bf2f(ushort u) {
  union { uint32_t u; float f; } v; v.u = ((uint32_t)u) << 16;
  return v.f;
}

// ---------------------------------------------------------------------------
// Kernel 0: blocks [0,2048): xb = bf16(x)   (grid-stride float4)
//           blocks [2048,2112): Wt[h][d][k] = bf16(W[h][k][d]) via LDS tile
// ---------------------------------------------------------------------------
__global__ __launch_bounds__(256) void convert(const float* __restrict__ x,
                                               const float* __restrict__ W,
                                               ushort* __restrict__ xb,
                                               ushort* __restrict__ Wt) {
  __shared__ float Ws[64][65];
  const int b = blockIdx.x, t = threadIdx.x;
  if (b < 2048) {
    const int gid = b * 256 + t;
    #pragma unroll
    for (int it = 0; it < 2; ++it) {
      const int q = gid + it * 524288;           // 2*524288 = 1,048,576 float4s
      const float4 v = ((const float4*)x)[q];
      ushort4 u;
      u.x = f2bf(v.x); u.y = f2bf(v.y); u.z = f2bf(v.z); u.w = f2bf(v.w);
      ((ushort4*)xb)[q] = u;
    }
  } else {
    const int bb = b - 2048;                     // 64 blocks = 8 heads x 8 k-tiles
    const int h = bb >> 3, kt = bb & 7;
    const int d = t & 63, krg = (t >> 6) * 16;
    const float* src = &W[((size_t)h * F_IN + kt * 64 + krg) * D_O + d];
    #pragma unroll
    for (int q = 0; q < 16; ++q)
      Ws[krg + q][d] = src[(size_t)q * D_O];     // coalesced over d
    __syncthreads();
    const int d0 = t >> 2, kq = (t & 3) * 16;
    ushort* dst = &Wt[(size_t)h * D_O * F_IN + (size_t)d0 * F_IN + kt * 64 + kq];
    #pragma unroll
    for (int q = 0; q < 16; ++q)
      dst[q] = f2bf(Ws[kq + q][d0]);             // coalesced over k
  }
}

// ---------------------------------------------------------------------------
// Kernel 1: Whb = bf16(xb @ Wt^T) + fused f1/f2 projections.
// 64x128 tile, BK=64, 512 blocks (2/CU), 4 waves (2x2): wave = 32 rows x 64 cols.
// Block (bx,by) owns heads {2bx,2bx+1} fully -> f1/f2 computed from f32 acc,
// 4 xor-shuffles reduce over the 16 lanes holding one row's 64 cols.
// ---------------------------------------------------------------------------
__global__ __launch_bounds__(256) void gemm_f(const ushort* __restrict__ xb,
                                              const ushort* __restrict__ Wt,
                                              const float* __restrict__ a1,
                                              const float* __restrict__ a2,
                                              ushort* __restrict__ Whb,
                                              float* __restrict__ f1,
                                              float* __restrict__ f2) {
  __shared__ ushort As[BM][BK + 8];
  __shared__ ushort Bs[BN][BK + 8];

  const int tid  = threadIdx.x;
  const int lane = tid & 63;
  const int wv   = tid >> 6;
  const int wr   = wv >> 1, wc = wv & 1;
  const int r0   = blockIdx.y * BM;
  const int c0   = blockIdx.x * BN;
  const int lm   = lane & 15;
  const int lg   = lane >> 4;

  f32x4 acc[2][4];
  #pragma unroll
  for (int m2 = 0; m2 < 2; ++m2)
    #pragma unroll
    for (int n2 = 0; n2 < 4; ++n2)
      acc[m2][n2] = (f32x4){0.f, 0.f, 0.f, 0.f};

  for (int k0 = 0; k0 < F_IN; k0 += BK) {
    __syncthreads();
    #pragma unroll
    for (int p = 0; p < 2; ++p) {                // A: 64x64 = 512 short8 chunks
      const int e = p * 256 + tid;
      const int row = e >> 3, ck = (e & 7) * 8;
      *(short8*)&As[row][ck] = *(const short8*)&xb[(size_t)(r0 + row) * F_IN + k0 + ck];
    }
    #pragma unroll
    for (int p = 0; p < 4; ++p) {                // B: 128x64 = 1024 chunks
      const int e = p * 256 + tid;
      const int row = e >> 3, ck = (e & 7) * 8;
      *(short8*)&Bs[row][ck] = *(const short8*)&Wt[(size_t)(c0 + row) * F_IN + k0 + ck];
    }
    __syncthreads();

    #pragma unroll
    for (int kk = 0; kk < 2; ++kk) {
      const int koff = kk * 32 + lg * 8;
      short8 af[2], bf[4];
      #pragma unroll
      for (int m2 = 0; m2 < 2; ++m2)
        af[m2] = *(const short8*)&As[wr * 32 + m2 * 16 + lm][koff];
      #pragma unroll
      for (int n2 = 0; n2 < 4; ++n2)
        bf[n2] = *(const short8*)&Bs[wc * 64 + n2 * 16 + lm][koff];
      #pragma unroll
      for (int m2 = 0; m2 < 2; ++m2)
        #pragma unroll
        for (int n2 = 0; n2 < 4; ++n2)
          acc[m2][n2] = __builtin_amdgcn_mfma_f32_16x16x32_bf16(af[m2], bf[n2], acc[m2][n2], 0, 0, 0);
    }
  }

  // ---- epilogue: Whb write + fused f1/f2 --------------------------------
  const int head = (c0 >> 6) + wc;               // bx*2 + wc
  float a1v[4], a2v[4];
  #pragma unroll
  for (int n2 = 0; n2 < 4; ++n2) {
    a1v[n2] = a1[head * D_O + n2 * 16 + lm];
    a2v[n2] = a2[head * D_O + n2 * 16 + lm];
  }

  #pragma unroll
  for (int m2 = 0; m2 < 2; ++m2) {
    #pragma unroll
    for (int r = 0; r < 4; ++r) {
      const int row = r0 + wr * 32 + m2 * 16 + lg * 4 + r;
      float p1 = 0.f, p2 = 0.f;
      #pragma unroll
      for (int n2 = 0; n2 < 4; ++n2) {
        const float v = acc[m2][n2][r];
        p1 += v * a1v[n2];
        p2 += v * a2v[n2];
        Whb[(size_t)row * NOUT + c0 + wc * 64 + n2 * 16 + lm] = f2bf(v);
      }
      #pragma unroll
      for (int o = 1; o < 16; o <<= 1) {
        p1 += __shfl_xor(p1, o);
        p2 += __shfl_xor(p2, o);
      }
      if (lm == 0) {
        f1[(size_t)row * H_N + head] = p1;
        f2[(size_t)row * H_N + head] = p2;
      }
    }
  }
}

// ---------------------------------------------------------------------------
// Kernel 2: one 256-thread block per row i.
// A) adj-row scan + deterministic compaction  B) logits  C) per-head softmax
// D) thread t accumulates cols {2t, 2t+1} over neighbors (ushort2 bf16 gather)
// ---------------------------------------------------------------------------
__global__ __launch_bounds__(256) void gat_attn(const uint32_t* __restrict__ adj,
                                                const ushort* __restrict__ Whb,
                                                const float* __restrict__ f1,
                                                const float* __restrict__ f2,
                                                float* __restrict__ out) {
  const int i    = blockIdx.x;
  const int tid  = threadIdx.x;
  const int lane = tid & 63;
  const int w    = tid >> 6;     // 0..3

  __shared__ int   nbr[MAXD];
  __shared__ float p[MAXD][9];
  __shared__ float f1s[8], invs[8];
  __shared__ int   wsum[4];

  if (tid < 8) f1s[tid] = f1[(size_t)i * H_N + tid];

  // --- A: scan + compaction ---------------------------------------------
  const uint32_t* arow = adj + (size_t)i * N_NODES;
  uint32_t bits = 0;
  #pragma unroll
  for (int u = 0; u < 8; ++u) {
    const uint4 a = *(const uint4*)&arow[(u * 256 + tid) * 4];
    if (a.x) bits |= 1u << (u * 4 + 0);
    if (a.y) bits |= 1u << (u * 4 + 1);
    if (a.z) bits |= 1u << (u * 4 + 2);
    if (a.w) bits |= 1u << (u * 4 + 3);
  }
  const int cnt = __popc(bits);
  int v = cnt;
  #pragma unroll
  for (int o = 1; o < 64; o <<= 1) {
    int u = __shfl_up(v, o);
    if (lane >= o) v += u;
  }
  if (lane == 63) wsum[w] = v;
  __syncthreads();
  int base = 0, total = 0;
  #pragma unroll
  for (int ww = 0; ww < 4; ++ww) {
    int s = wsum[ww];
    if (ww < w) base += s;
    total += s;
  }
  const int deg = min(total, MAXD);
  int off = base + v - cnt;
  #pragma unroll
  for (int u = 0; u < 8; ++u)
    #pragma unroll
    for (int bq = 0; bq < 4; ++bq)
      if (bits & (1u << (u * 4 + bq))) {
        if (off < MAXD) nbr[off] = (u * 256 + tid) * 4 + bq;
        ++off;
      }
  __syncthreads();

  // --- B: logits ---------------------------------------------------------
  for (int idx = tid; idx < deg * H_N; idx += 256) {
    const int n = idx >> 3, h = idx & 7;
    const int j = nbr[n];
    float l = f1s[h] + f2[(size_t)j * H_N + h];
    l = l > 0.f ? l : 0.2f * l;
    p[n][h] = l;
  }
  __syncthreads();

  // --- C: softmax (wave w handles heads w and w+4) -----------------------
  #pragma unroll
  for (int hh = 0; hh < 2; ++hh) {
    const int h = w + hh * 4;
    float m = -3.0e38f;
    for (int n = lane; n < deg; n += 64) m = fmaxf(m, p[n][h]);
    #pragma unroll
    for (int o = 32; o; o >>= 1) m = fmaxf(m, __shfl_xor(m, o));
    float s = 0.f;
    for (int n = lane; n < deg; n += 64) {
      const float e = __expf(p[n][h] - m);
      p[n][h] = e;
      s += e;
    }
    #pragma unroll
    for (int o = 32; o; o >>= 1) s += __shfl_xor(s, o);
    if (lane == 0) invs[h] = 1.0f / s;
  }
  __syncthreads();

  // --- D: weighted accumulation (2 cols per thread, bf16 gather) ---------
  const int h = tid >> 5;                     // (2*tid)/64
  float acc0 = 0.f, acc1 = 0.f;
  #pragma unroll 8
  for (int n = 0; n < deg; ++n) {
    const float pv = p[n][h];
    const ushort2 u = *(const ushort2*)&Whb[(size_t)nbr[n] * NOUT + tid * 2];
    acc0 += pv * bf2f(u.x);
    acc1 += pv * bf2f(u.y);
  }
  const float inv = invs[h];
  float2 o2; o2.x = acc0 * inv; o2.y = acc1 * inv;
  *(float2*)&out[(size_t)i * NOUT + tid * 2] = o2;
}

extern "C" void kernel_launch(void* const* d_in, const int* in_sizes, int n_in,
                              void* d_out, int out_size, void* d_ws, size_t ws_size,
                              hipStream_t stream) {
  const float* x   = (const float*)d_in[0];
  const float* adj = (const float*)d_in[1];
  const float* W   = (const float*)d_in[2];
  const float* a1  = (const float*)d_in[3];
  const float* a2  = (const float*)d_in[4];
  float* out = (float*)d_out;

  ushort* Whb = (ushort*)d_ws;                          // 4M bf16 = 8 MB
  ushort* xb  = Whb + (size_t)N_NODES * NOUT;           // 4M bf16 = 8 MB
  ushort* Wt  = xb + (size_t)N_NODES * F_IN;            // 256K bf16 = 0.5 MB
  float*  f1  = (float*)(Wt + (size_t)H_N * D_O * F_IN);
  float*  f2  = f1 + (size_t)N_NODES * H_N;

  hipLaunchKernelGGL(convert, dim3(2112), dim3(256), 0, stream, x, W, xb, Wt);
  hipLaunchKernelGGL(gemm_f, dim3(NOUT / BN, N_NODES / BM), dim3(256), 0, stream,
                     xb, Wt, a1, a2, Whb, f1, f2);
  hipLaunchKernelGGL(gat_attn, dim3(N_NODES), dim3(256), 0, stream,
                     (const uint32_t*)adj, Whb, f1, f2, out);
}